// Round 9
// baseline (267.008 us; speedup 1.0000x reference)
//
#include <hip/hip_runtime.h>

#define NBINS 50
#define PAD_G 100
#define TPB 256
#define TILE_CHUNKS 512   // float4 chunks per tile per block (8 KB)
#define GRID 2560         // 8 blocks/CU resident (LDS 18.4 KB allows 8); was 5
#define STEPS 5           // GRID*STEPS*TILE_CHUNKS == nvec exactly
#define PIPE 4            // LDS buffers; 3 tiles in flight (R0-proven)

typedef float vf4 __attribute__((ext_vector_type(4)));

// Gaussian kernel (5 taps, sigma=0.5), normalized
#define K0 2.6387004e-4f
#define K1 1.0645079e-1f
#define K2 7.8657085e-1f

__device__ __forceinline__ unsigned quant(int g) {
  int d = g - 50;
  d = (d < 0) ? 0 : d;
  unsigned q = __umul24((unsigned)d, 10923u) >> 16;  // exact /6 for this range
  return (q > NBINS - 1) ? (NBINS - 1) : q;
}

__device__ __forceinline__ float softplus_stable(float x) {
  return fmaxf(x, 0.f) + __logf(1.f + __expf(-fabsf(x)));
}

// qv2[f]: low byte = code(frame f), high byte = code(frame f+1); 255 = padded.
// Atomic-free (R6 lesson: one same-address atomicAdd per wave cost 96us).
// Vectorized: 4 frames/thread, int4 in, ushort4 out.
__global__ __launch_bounds__(256) void pitch_pre(
    const int* __restrict__ gt, unsigned short* __restrict__ qv2, int n)
{
  const int base = (blockIdx.x * blockDim.x + threadIdx.x) << 2;
  if (base >= n) return;
  if (base + 4 <= n) {
    const int4 g = *reinterpret_cast<const int4*>(gt + base);
    const int g4 = (base + 4 < n) ? gt[base + 4] : gt[n - 1];
    const unsigned c0 = (g.x == PAD_G) ? 255u : quant(g.x);
    const unsigned c1 = (g.y == PAD_G) ? 255u : quant(g.y);
    const unsigned c2 = (g.z == PAD_G) ? 255u : quant(g.z);
    const unsigned c3 = (g.w == PAD_G) ? 255u : quant(g.w);
    const unsigned c4 = (g4  == PAD_G) ? 255u : quant(g4);
    ushort4 o;
    o.x = (unsigned short)(c0 | (c1 << 8));
    o.y = (unsigned short)(c1 | (c2 << 8));
    o.z = (unsigned short)(c2 | (c3 << 8));
    o.w = (unsigned short)(c3 | (c4 << 8));
    *reinterpret_cast<ushort4*>(qv2 + base) = o;
  } else {
    for (int f = base; f < n; ++f) {           // generic tail (empty here)
      const int ga = gt[f];
      const int gb = gt[(f + 1 < n) ? f + 1 : n - 1];
      const unsigned ba = (ga == PAD_G) ? 255u : quant(ga);
      const unsigned bb = (gb == PAD_G) ? 255u : quant(gb);
      qv2[f] = (unsigned short)(ba | (bb << 8));
    }
  }
}

// s_tab layout: 51 rows x 8 cols. Row q (q<50): col d1 holds the blur weight
// for output bin j = q - 2 + (d1-1); cols 0,6,7 are zero. Row 50 is all zero
// (absorbs pad code 255). Lookup: clamp(j - c + 3, 0, 7); out-of-range taps
// land on zero entries -- saves the (dj<5) cmp+cndmask of the old 50x5 table.
__device__ __forceinline__ void consume_chunk(
    vf4 p, unsigned q2, int j0, const float* s_tab,
    float& num, unsigned& cnt)
{
  const unsigned c0 = q2 & 255u;
  const unsigned c1 = (q2 >> 8) & 255u;
#pragma unroll
  for (int u = 0; u < 4; ++u) {
    int j = j0 + u;
    const bool wrap = (j >= NBINS);
    const unsigned c = wrap ? c1 : c0;
    j = wrap ? j - NBINS : j;
    const float x = p[u];
    const float sp = softplus_stable(x);
    const unsigned qc = (c > 50u) ? 50u : c;   // 255 -> zero row
    int dj = j - (int)c + 3;                   // tap offset +2, bias +1
    dj = dj < 0 ? 0 : (dj > 7 ? 7 : dj);
    const float t = s_tab[(qc << 3) + dj];
    const bool valid = (c != 255u);
    num += valid ? __builtin_fmaf(-x, t, sp) : 0.f;
    cnt += valid ? 1u : 0u;
  }
}

__global__ __launch_bounds__(TPB) void pitch_loss_main(
    const vf4* __restrict__ preds4,
    const unsigned short* __restrict__ qv2,
    int nvec, int total, int ntiles, int nblocks,
    float* __restrict__ acc,     // [0]=num(float) [1]=cnt(uint) [2]=ctr(uint)
    float* __restrict__ out)
{
  __shared__ vf4 buf[PIPE][TILE_CHUNKS / 2];   // 4 x 4 KB (DMA half only)
  __shared__ float s_tab[51 * 8];

  for (int idx = threadIdx.x; idx < 51 * 8; idx += TPB) {
    const int q = idx >> 3;
    const int dt = (idx & 7) - 1;        // tap offset in [-1..6]; valid 0..4
    float t = 0.f;
    if (q < NBINS && 0 <= dt && dt < 5) {
      const int j = q - 2 + dt;
      if (0 <= j && j < NBINS) {
        const float kk[5] = {K0, K1, K2, K1, K0};
#pragma unroll
        for (int i = 0; i < 5; ++i) {
          int m = j - 2 + i;
          m = (m < 0) ? -m : m;
          m = (m > NBINS - 1) ? 2 * (NBINS - 1) - m : m;
          if (m == q) t += kk[i];
        }
      }
    }
    s_tab[idx] = t;
  }
  __syncthreads();

  const int wave = threadIdx.x >> 6;
  const int lane = threadIdx.x & 63;

  float num = 0.f;
  unsigned cnt = 0;
  vf4 pr[PIPE];                 // direct-nt half (VGPR path)
  unsigned uu[PIPE][2];         // staged frame-codes (compile-time indexed)

  // Dual-path stage (R0-proven): per wave per tile, chunks [wave*128,+64)
  // via global_load_lds (1 KB/instr), chunks [+64,+128) via direct
  // nontemporal 16B loads. R7 profiling: dur identical whether preds came
  // from HBM (53 MB FETCH) or was fully L3-resident (0.1 MB) -> the wall
  // is CU-side concurrency, ~0.03 TB/s per resident wave per path, paths
  // additive, ~linear in waves. This round: 8 blocks/CU (was 5).
  auto STAGE = [&](int t, int bb) {
    const int tc = (t < ntiles) ? t : ntiles - 1;   // exact fit: no-op clamp
    const int cb = tc * TILE_CHUNKS + wave * 128 + lane;
    __builtin_amdgcn_global_load_lds(
        (const __attribute__((address_space(1))) void*)(const void*)(preds4 + cb),
        (__attribute__((address_space(3))) void*)(void*)&buf[bb][wave * 64],
        16, 0, 0);
    pr[bb] = __builtin_nontemporal_load(preds4 + cb + 64);
    const unsigned f0 = (unsigned)(cb << 2) / 50u;           // magic-mul
    const unsigned f1 = (unsigned)((cb + 64) << 2) / 50u;
    const unsigned qa = qv2[f0];
    const unsigned qb = qv2[f1];
    uu[bb][0] = (t < ntiles) ? qa : 0xFFFFu;
    uu[bb][1] = (t < ntiles) ? qb : 0xFFFFu;
  };

  auto COMPUTE = [&](int t, int bb) {
    const int tc = (t < ntiles) ? t : ntiles - 1;
    const int cb = tc * TILE_CHUNKS + wave * 128 + lane;
    const vf4 p0 = buf[bb][wave * 64 + lane];       // ds_read_b128
    const int e0 = cb << 2;
    const unsigned f0 = (unsigned)e0 / 50u;
    consume_chunk(p0, uu[bb][0], e0 - (int)f0 * 50, s_tab, num, cnt);
    const vf4 p1 = pr[bb];
    const int e1 = e0 + 256;
    const unsigned f1 = (unsigned)e1 / 50u;
    consume_chunk(p1, uu[bb][1], e1 - (int)f1 * 50, s_tab, num, cnt);
  };

  // wave-private pipeline, 3 tiles in flight, no barriers in the loop.
  // STEPS and all bb indices are compile-time -> pr/uu stay in registers.
  STAGE(blockIdx.x, 0);
  STAGE(blockIdx.x + nblocks, 1);
  STAGE(blockIdx.x + 2 * nblocks, 2);
#pragma unroll
  for (int s = 0; s < STEPS; ++s) {
    const int bb = s & 3;
    if (s + 3 < STEPS) {
      STAGE(blockIdx.x + (s + 3) * nblocks, (s + 3) & 3);
      // 3 younger groups (12 vmem ops) in flight; group s drained
      asm volatile("s_waitcnt vmcnt(12)" ::: "memory");
    } else if (s + 2 < STEPS) {
      asm volatile("s_waitcnt vmcnt(8)" ::: "memory");
    } else if (s + 1 < STEPS) {
      asm volatile("s_waitcnt vmcnt(4)" ::: "memory");
    } else {
      asm volatile("s_waitcnt vmcnt(0)" ::: "memory");
    }
    COMPUTE(blockIdx.x + s * nblocks, bb);
  }

  // generic tails (empty at 26,214,400)
  const int tid = blockIdx.x * TPB + threadIdx.x;
  const int nthreads = nblocks * TPB;
  for (int v = ntiles * TILE_CHUNKS + tid; v < nvec; v += nthreads) {
    const int e0 = v << 2;
    const unsigned f = (unsigned)e0 / 50u;
    const vf4 p = preds4[v];
    consume_chunk(p, qv2[f], e0 - (int)f * 50, s_tab, num, cnt);
  }
  for (int e = (nvec << 2) + tid; e < total; e += nthreads) {
    const unsigned f = (unsigned)e / 50u;
    const int j = e - (int)f * 50;
    const unsigned c = qv2[f] & 255u;
    if (c != 255u) {
      const unsigned qc = (c > 50u) ? 50u : c;
      int dj = j - (int)c + 3;
      dj = dj < 0 ? 0 : (dj > 7 ? 7 : dj);
      const float t = s_tab[(qc << 3) + dj];
      const float x = ((const float*)preds4)[e];
      num += softplus_stable(x) - x * t;
      cnt += 1u;
    }
  }

  // wave-64 reduction, then one atomic per block
#pragma unroll
  for (int off = 32; off > 0; off >>= 1) {
    num += __shfl_down(num, off, 64);
    cnt += __shfl_down(cnt, off, 64);
  }
  __shared__ float sn[4];
  __shared__ unsigned sc[4];
  if (lane == 0) { sn[wave] = num; sc[wave] = cnt; }
  __syncthreads();
  if (threadIdx.x == 0) {
    const float n = sn[0] + sn[1] + sn[2] + sn[3];
    const unsigned cc = sc[0] + sc[1] + sc[2] + sc[3];
    atomicAdd(&acc[0], n);
    atomicAdd((unsigned*)&acc[1], cc);
    __threadfence();
    const unsigned done = atomicAdd((unsigned*)&acc[2], 1u);
    if (done == (unsigned)nblocks - 1u) {
      const float tn = atomicAdd(&acc[0], 0.f);
      const unsigned tc = atomicAdd((unsigned*)&acc[1], 0u);
      out[0] = tn / (float)tc;
    }
  }
}

extern "C" void kernel_launch(void* const* d_in, const int* in_sizes, int n_in,
                              void* d_out, int out_size, void* d_ws, size_t ws_size,
                              hipStream_t stream) {
  const vf4* preds4 = (const vf4*)d_in[0];
  const int* gt = (const int*)d_in[1];
  float* out = (float*)d_out;
  float* acc = (float*)d_ws;                                   // 12 B
  unsigned short* qv2 = (unsigned short*)((char*)d_ws + 256);  // 1 MB
  const int total = in_sizes[0];     // 26214400
  const int nframes = in_sizes[1];   // 524288
  const int nvec = total >> 2;       // 6553600
  const int ntiles = nvec / TILE_CHUNKS;  // 12800 == GRID*STEPS

  (void)hipMemsetAsync(acc, 0, 3 * sizeof(float), stream);

  const int pre_groups = (nframes + 3) >> 2;
  pitch_pre<<<(pre_groups + 255) / 256, 256, 0, stream>>>(gt, qv2, nframes);

  pitch_loss_main<<<GRID, TPB, 0, stream>>>(
      preds4, qv2, nvec, total, ntiles, GRID, acc, out);
}

// Round 10
// 205.107 us; speedup vs baseline: 1.3018x; 1.3018x over previous
//
#include <hip/hip_runtime.h>

#define NBINS 50
#define PAD_G 100
#define TPB 256
#define TILE_CHUNKS 1024  // float4 chunks per tile per block (16 KB)
#define GRID 1280
#define STEPS 5           // GRID*STEPS*TILE_CHUNKS == nvec exactly
#define PIPE 3            // LDS buffers; 2 tiles in flight

typedef float vf4 __attribute__((ext_vector_type(4)));

// Gaussian kernel (5 taps, sigma=0.5), normalized
#define K0 2.6387004e-4f
#define K1 1.0645079e-1f
#define K2 7.8657085e-1f

__device__ __forceinline__ unsigned quant(int g) {
  int d = g - 50;
  d = (d < 0) ? 0 : d;
  unsigned q = __umul24((unsigned)d, 10923u) >> 16;  // exact /6 for this range
  return (q > NBINS - 1) ? (NBINS - 1) : q;
}

__device__ __forceinline__ float softplus_stable(float x) {
  return fmaxf(x, 0.f) + __logf(1.f + __expf(-fabsf(x)));
}

// qv2[f]: low byte = code(frame f), high byte = code(frame f+1); 255 = padded.
// Atomic-free (R6 lesson). Vectorized: 4 frames/thread.
__global__ __launch_bounds__(256) void pitch_pre(
    const int* __restrict__ gt, unsigned short* __restrict__ qv2, int n)
{
  const int base = (blockIdx.x * blockDim.x + threadIdx.x) << 2;
  if (base >= n) return;
  if (base + 4 <= n) {
    const int4 g = *reinterpret_cast<const int4*>(gt + base);
    const int g4 = (base + 4 < n) ? gt[base + 4] : gt[n - 1];
    const unsigned c0 = (g.x == PAD_G) ? 255u : quant(g.x);
    const unsigned c1 = (g.y == PAD_G) ? 255u : quant(g.y);
    const unsigned c2 = (g.z == PAD_G) ? 255u : quant(g.z);
    const unsigned c3 = (g.w == PAD_G) ? 255u : quant(g.w);
    const unsigned c4 = (g4  == PAD_G) ? 255u : quant(g4);
    ushort4 o;
    o.x = (unsigned short)(c0 | (c1 << 8));
    o.y = (unsigned short)(c1 | (c2 << 8));
    o.z = (unsigned short)(c2 | (c3 << 8));
    o.w = (unsigned short)(c3 | (c4 << 8));
    *reinterpret_cast<ushort4*>(qv2 + base) = o;
  } else {
    for (int f = base; f < n; ++f) {
      const int ga = gt[f];
      const int gb = gt[(f + 1 < n) ? f + 1 : n - 1];
      const unsigned ba = (ga == PAD_G) ? 255u : quant(ga);
      const unsigned bb = (gb == PAD_G) ? 255u : quant(gb);
      qv2[f] = (unsigned short)(ba | (bb << 8));
    }
  }
}

// s_tab: 51 rows x 8 cols, zero-padded; row 50 all-zero absorbs pad code 255.
__device__ __forceinline__ void consume_chunk(
    vf4 p, unsigned q2, int j0, const float* s_tab,
    float& num, unsigned& cnt)
{
  const unsigned c0 = q2 & 255u;
  const unsigned c1 = (q2 >> 8) & 255u;
#pragma unroll
  for (int u = 0; u < 4; ++u) {
    int j = j0 + u;
    const bool wrap = (j >= NBINS);
    const unsigned c = wrap ? c1 : c0;
    j = wrap ? j - NBINS : j;
    const float x = p[u];
    const float sp = softplus_stable(x);
    const unsigned qc = (c > 50u) ? 50u : c;   // 255 -> zero row
    int dj = j - (int)c + 3;
    dj = dj < 0 ? 0 : (dj > 7 ? 7 : dj);
    const float t = s_tab[(qc << 3) + dj];
    const bool valid = (c != 255u);
    num += valid ? __builtin_fmaf(-x, t, sp) : 0.f;
    cnt += valid ? 1u : 0u;
  }
}

__global__ __launch_bounds__(TPB) void pitch_loss_main(
    const vf4* __restrict__ preds4,
    const unsigned short* __restrict__ qv2,
    int nvec, int total, int ntiles, int nblocks,
    float* __restrict__ acc,     // [0]=num(float) [1]=cnt(uint) [2]=ctr(uint)
    float* __restrict__ out)
{
  // per buffer: 4 waves x 128 chunks x 16B = 8 KB; 3 buffers = 24 KB
  __shared__ vf4 buf[PIPE][TILE_CHUNKS / 2];
  __shared__ float s_tab[51 * 8];

  for (int idx = threadIdx.x; idx < 51 * 8; idx += TPB) {
    const int q = idx >> 3;
    const int dt = (idx & 7) - 1;
    float t = 0.f;
    if (q < NBINS && 0 <= dt && dt < 5) {
      const int j = q - 2 + dt;
      if (0 <= j && j < NBINS) {
        const float kk[5] = {K0, K1, K2, K1, K0};
#pragma unroll
        for (int i = 0; i < 5; ++i) {
          int m = j - 2 + i;
          m = (m < 0) ? -m : m;
          m = (m > NBINS - 1) ? 2 * (NBINS - 1) - m : m;
          if (m == q) t += kk[i];
        }
      }
    }
    s_tab[idx] = t;
  }
  __syncthreads();

  const int wave = threadIdx.x >> 6;
  const int lane = threadIdx.x & 63;

  float num = 0.f;
  unsigned cnt = 0;
  vf4 pr[PIPE][2];              // two direct-nt chunks per slot
  unsigned uu[PIPE][2];         // four packed frame-codes per slot

  // R9 post-mortem law: a CU retires ~1 wave stage-group per ~900 cy,
  // nearly independent of wave count and payload -> maximize BYTES per
  // stage-group. R7 carried 2 KB/group (2 paths x 1 KB) -> 1.2 TB/s.
  // This round: 4 KB/group (2x DMA + 2x direct-nt per wave), same
  // skeleton (GRID=1280, dual-path, wave-private vmcnt ladder).
  // Per wave per tile: 256 chunks: [0,64) DMA-A, [64,128) direct-A,
  // [128,192) DMA-B, [192,256) direct-B.
  auto STAGE = [&](int t, int bb) {
    const int tc = (t < ntiles) ? t : ntiles - 1;   // exact fit: no-op clamp
    const int cb = tc * TILE_CHUNKS + wave * 256 + lane;
    __builtin_amdgcn_global_load_lds(
        (const __attribute__((address_space(1))) void*)(const void*)(preds4 + cb),
        (__attribute__((address_space(3))) void*)(void*)&buf[bb][wave * 128],
        16, 0, 0);
    pr[bb][0] = __builtin_nontemporal_load(preds4 + cb + 64);
    __builtin_amdgcn_global_load_lds(
        (const __attribute__((address_space(1))) void*)(const void*)(preds4 + cb + 128),
        (__attribute__((address_space(3))) void*)(void*)&buf[bb][wave * 128 + 64],
        16, 0, 0);
    pr[bb][1] = __builtin_nontemporal_load(preds4 + cb + 192);
    const unsigned fA0 = (unsigned)(cb << 2) / 50u;            // magic-mul
    const unsigned fA1 = (unsigned)((cb + 64) << 2) / 50u;
    const unsigned fB0 = (unsigned)((cb + 128) << 2) / 50u;
    const unsigned fB1 = (unsigned)((cb + 192) << 2) / 50u;
    const unsigned qa = qv2[fA0];
    const unsigned qb = qv2[fA1];
    const unsigned qc_ = qv2[fB0];
    const unsigned qd = qv2[fB1];
    uu[bb][0] = (t < ntiles) ? (qa | (qb << 16)) : 0xFFFFFFFFu;
    uu[bb][1] = (t < ntiles) ? (qc_ | (qd << 16)) : 0xFFFFFFFFu;
  };

  auto COMPUTE = [&](int t, int bb) {
    const int tc = (t < ntiles) ? t : ntiles - 1;
    const int cb = tc * TILE_CHUNKS + wave * 256 + lane;
    const int e0 = cb << 2;
    {
      const vf4 p = buf[bb][wave * 128 + lane];            // ds_read_b128
      const unsigned f = (unsigned)e0 / 50u;
      consume_chunk(p, uu[bb][0] & 0xFFFFu, e0 - (int)f * 50, s_tab, num, cnt);
    }
    {
      const vf4 p = pr[bb][0];
      const int e = e0 + 256;
      const unsigned f = (unsigned)e / 50u;
      consume_chunk(p, uu[bb][0] >> 16, e - (int)f * 50, s_tab, num, cnt);
    }
    {
      const vf4 p = buf[bb][wave * 128 + 64 + lane];       // ds_read_b128
      const int e = e0 + 512;
      const unsigned f = (unsigned)e / 50u;
      consume_chunk(p, uu[bb][1] & 0xFFFFu, e - (int)f * 50, s_tab, num, cnt);
    }
    {
      const vf4 p = pr[bb][1];
      const int e = e0 + 768;
      const unsigned f = (unsigned)e / 50u;
      consume_chunk(p, uu[bb][1] >> 16, e - (int)f * 50, s_tab, num, cnt);
    }
  };

  // wave-private pipeline, 2 tiles in flight, no barriers in the loop.
  // Stage group = 8 vmem ops (2 DMA + 2 dwordx4 + 4 ushort).
  // All slot indices compile-time (rule #20).
  STAGE(blockIdx.x, 0);
  STAGE(blockIdx.x + nblocks, 1);
#pragma unroll
  for (int s = 0; s < STEPS; ++s) {
    const int bb = s % PIPE;
    if (s + 2 < STEPS) {
      STAGE(blockIdx.x + (s + 2) * nblocks, (s + 2) % PIPE);
      // 2 younger groups (16 vmem ops) in flight; group s drained
      asm volatile("s_waitcnt vmcnt(16)" ::: "memory");
    } else if (s + 1 < STEPS) {
      asm volatile("s_waitcnt vmcnt(8)" ::: "memory");
    } else {
      asm volatile("s_waitcnt vmcnt(0)" ::: "memory");
    }
    COMPUTE(blockIdx.x + s * nblocks, bb);
  }

  // generic tails (empty at 26,214,400: exact fit)
  const int tid = blockIdx.x * TPB + threadIdx.x;
  const int nthreads = nblocks * TPB;
  for (int v = ntiles * TILE_CHUNKS + tid; v < nvec; v += nthreads) {
    const int e0 = v << 2;
    const unsigned f = (unsigned)e0 / 50u;
    const vf4 p = preds4[v];
    consume_chunk(p, qv2[f], e0 - (int)f * 50, s_tab, num, cnt);
  }
  for (int e = (nvec << 2) + tid; e < total; e += nthreads) {
    const unsigned f = (unsigned)e / 50u;
    const int j = e - (int)f * 50;
    const unsigned c = qv2[f] & 255u;
    if (c != 255u) {
      const unsigned qc = (c > 50u) ? 50u : c;
      int dj = j - (int)c + 3;
      dj = dj < 0 ? 0 : (dj > 7 ? 7 : dj);
      const float t = s_tab[(qc << 3) + dj];
      const float x = ((const float*)preds4)[e];
      num += softplus_stable(x) - x * t;
      cnt += 1u;
    }
  }

  // wave-64 reduction, then one atomic per block
#pragma unroll
  for (int off = 32; off > 0; off >>= 1) {
    num += __shfl_down(num, off, 64);
    cnt += __shfl_down(cnt, off, 64);
  }
  __shared__ float sn[4];
  __shared__ unsigned sc[4];
  if (lane == 0) { sn[wave] = num; sc[wave] = cnt; }
  __syncthreads();
  if (threadIdx.x == 0) {
    const float n = sn[0] + sn[1] + sn[2] + sn[3];
    const unsigned cc = sc[0] + sc[1] + sc[2] + sc[3];
    atomicAdd(&acc[0], n);
    atomicAdd((unsigned*)&acc[1], cc);
    __threadfence();
    const unsigned done = atomicAdd((unsigned*)&acc[2], 1u);
    if (done == (unsigned)nblocks - 1u) {
      const float tn = atomicAdd(&acc[0], 0.f);
      const unsigned tc = atomicAdd((unsigned*)&acc[1], 0u);
      out[0] = tn / (float)tc;
    }
  }
}

extern "C" void kernel_launch(void* const* d_in, const int* in_sizes, int n_in,
                              void* d_out, int out_size, void* d_ws, size_t ws_size,
                              hipStream_t stream) {
  const vf4* preds4 = (const vf4*)d_in[0];
  const int* gt = (const int*)d_in[1];
  float* out = (float*)d_out;
  float* acc = (float*)d_ws;                                   // 12 B
  unsigned short* qv2 = (unsigned short*)((char*)d_ws + 256);  // 1 MB
  const int total = in_sizes[0];     // 26214400
  const int nframes = in_sizes[1];   // 524288
  const int nvec = total >> 2;       // 6553600
  const int ntiles = nvec / TILE_CHUNKS;  // 6400 == GRID*STEPS

  (void)hipMemsetAsync(acc, 0, 3 * sizeof(float), stream);

  const int pre_groups = (nframes + 3) >> 2;
  pitch_pre<<<(pre_groups + 255) / 256, 256, 0, stream>>>(gt, qv2, nframes);

  pitch_loss_main<<<GRID, TPB, 0, stream>>>(
      preds4, qv2, nvec, total, ntiles, GRID, acc, out);
}

// Round 11
// 203.187 us; speedup vs baseline: 1.3141x; 1.0094x over previous
//
#include <hip/hip_runtime.h>

#define NBINS 50
#define PAD_G 100
#define TPB 256
#define TILE_CHUNKS 512   // float4 chunks per tile per block (8 KB)
#define GRID 1280
#define STEPS 10          // GRID*STEPS*TILE_CHUNKS == nvec exactly
#define PIPE 4            // LDS buffers; 3 tiles in flight (R0/R7-proven)

typedef float vf4 __attribute__((ext_vector_type(4)));

// Gaussian kernel (5 taps, sigma=0.5), normalized
#define K0 2.6387004e-4f
#define K1 1.0645079e-1f
#define K2 7.8657085e-1f

__device__ __forceinline__ unsigned quant(int g) {
  int d = g - 50;
  d = (d < 0) ? 0 : d;
  unsigned q = __umul24((unsigned)d, 10923u) >> 16;  // exact /6 for this range
  return (q > NBINS - 1) ? (NBINS - 1) : q;
}

__device__ __forceinline__ float softplus_stable(float x) {
  return fmaxf(x, 0.f) + __logf(1.f + __expf(-fabsf(x)));
}

// qv2[f]: low byte = code(frame f), high byte = code(frame f+1); 255 = padded.
// Atomic-free (R6 lesson). Also zeroes acc (replaces the memset dispatch;
// stream order guarantees completion before pitch_loss_main).
__global__ __launch_bounds__(256) void pitch_pre(
    const int* __restrict__ gt, unsigned short* __restrict__ qv2, int n,
    unsigned* __restrict__ acc)
{
  if (blockIdx.x == 0 && threadIdx.x < 3) acc[threadIdx.x] = 0u;
  const int base = (blockIdx.x * blockDim.x + threadIdx.x) << 2;
  if (base >= n) return;
  if (base + 4 <= n) {
    const int4 g = *reinterpret_cast<const int4*>(gt + base);
    const int g4 = (base + 4 < n) ? gt[base + 4] : gt[n - 1];
    const unsigned c0 = (g.x == PAD_G) ? 255u : quant(g.x);
    const unsigned c1 = (g.y == PAD_G) ? 255u : quant(g.y);
    const unsigned c2 = (g.z == PAD_G) ? 255u : quant(g.z);
    const unsigned c3 = (g.w == PAD_G) ? 255u : quant(g.w);
    const unsigned c4 = (g4  == PAD_G) ? 255u : quant(g4);
    ushort4 o;
    o.x = (unsigned short)(c0 | (c1 << 8));
    o.y = (unsigned short)(c1 | (c2 << 8));
    o.z = (unsigned short)(c2 | (c3 << 8));
    o.w = (unsigned short)(c3 | (c4 << 8));
    *reinterpret_cast<ushort4*>(qv2 + base) = o;
  } else {
    for (int f = base; f < n; ++f) {           // generic tail (empty here)
      const int ga = gt[f];
      const int gb = gt[(f + 1 < n) ? f + 1 : n - 1];
      const unsigned ba = (ga == PAD_G) ? 255u : quant(ga);
      const unsigned bb = (gb == PAD_G) ? 255u : quant(gb);
      qv2[f] = (unsigned short)(ba | (bb << 8));
    }
  }
}

// s_tab: 51 rows x 8 cols, zero-padded; row 50 all-zero absorbs pad code 255.
// Lookup: clamp(j - c + 3, 0, 7); out-of-range taps land on zeros.

// 8 consecutive elements (one lane's DMA chunk + direct chunk), spanning at
// most one frame boundary -> ONE packed code pair covers all 8.
__device__ __forceinline__ void consume8(
    vf4 pa, vf4 pb, unsigned q2, int j0, const float* s_tab,
    float& num, unsigned& cnt)
{
  const unsigned c_lo = q2 & 255u;
  const unsigned c_hi = (q2 >> 8) & 255u;
#pragma unroll
  for (int u = 0; u < 8; ++u) {
    int j = j0 + u;                            // j0 <= 49, j0+7 <= 56: <=1 wrap
    const bool wrap = (j >= NBINS);
    const unsigned c = wrap ? c_hi : c_lo;
    j = wrap ? j - NBINS : j;
    const float x = (u < 4) ? pa[u] : pb[u - 4];
    const float sp = softplus_stable(x);
    const unsigned qc = (c > 50u) ? 50u : c;   // 255 -> zero row
    int dj = j - (int)c + 3;
    dj = dj < 0 ? 0 : (dj > 7 ? 7 : dj);
    const float t = s_tab[(qc << 3) + dj];
    const bool valid = (c != 255u);
    num += valid ? __builtin_fmaf(-x, t, sp) : 0.f;
    cnt += valid ? 1u : 0u;
  }
}

// 4-element variant for generic tails (empty at this shape)
__device__ __forceinline__ void consume_chunk(
    vf4 p, unsigned q2, int j0, const float* s_tab,
    float& num, unsigned& cnt)
{
  const unsigned c0 = q2 & 255u;
  const unsigned c1 = (q2 >> 8) & 255u;
#pragma unroll
  for (int u = 0; u < 4; ++u) {
    int j = j0 + u;
    const bool wrap = (j >= NBINS);
    const unsigned c = wrap ? c1 : c0;
    j = wrap ? j - NBINS : j;
    const float x = p[u];
    const float sp = softplus_stable(x);
    const unsigned qc = (c > 50u) ? 50u : c;
    int dj = j - (int)c + 3;
    dj = dj < 0 ? 0 : (dj > 7 ? 7 : dj);
    const float t = s_tab[(qc << 3) + dj];
    const bool valid = (c != 255u);
    num += valid ? __builtin_fmaf(-x, t, sp) : 0.f;
    cnt += valid ? 1u : 0u;
  }
}

__global__ __launch_bounds__(TPB) void pitch_loss_main(
    const vf4* __restrict__ preds4,
    const unsigned short* __restrict__ qv2,
    int nvec, int total, int ntiles, int nblocks,
    float* __restrict__ acc,     // [0]=num(float) [1]=cnt(uint) [2]=ctr(uint)
    float* __restrict__ out)
{
  __shared__ vf4 buf[PIPE][TILE_CHUNKS / 2];   // 4 x 4 KB (DMA half only)
  __shared__ float s_tab[51 * 8];

  for (int idx = threadIdx.x; idx < 51 * 8; idx += TPB) {
    const int q = idx >> 3;
    const int dt = (idx & 7) - 1;        // tap offset in [-1..6]; valid 0..4
    float t = 0.f;
    if (q < NBINS && 0 <= dt && dt < 5) {
      const int j = q - 2 + dt;
      if (0 <= j && j < NBINS) {
        const float kk[5] = {K0, K1, K2, K1, K0};
#pragma unroll
        for (int i = 0; i < 5; ++i) {
          int m = j - 2 + i;
          m = (m < 0) ? -m : m;
          m = (m > NBINS - 1) ? 2 * (NBINS - 1) - m : m;
          if (m == q) t += kk[i];
        }
      }
    }
    s_tab[idx] = t;
  }
  __syncthreads();

  const int wave = threadIdx.x >> 6;
  const int lane = threadIdx.x & 63;

  float num = 0.f;
  unsigned cnt = 0;
  vf4 pr[PIPE];                 // direct-nt chunk (VGPR path)
  unsigned uu[PIPE];            // ONE packed code pair per slot (was two)
  int jj[PIPE];                 // j0 per slot (div done once, in STAGE)

  // R10 post-mortem: R7 and R10 moved the SAME vmem instruction count
  // (40/thread) but R10 (8 fat instrs/group) lost 36% -> the binding
  // resource looks like the vmem instruction stream, and half of R7's
  // stream was 2-byte qv2 loads. This round: interleave the dual paths
  // at chunk granularity -- lane L stages chunk 2L via global_load_lds
  // (per-lane global src is legal; LDS dest stays linear base+lane*16)
  // and chunk 2L+1 via direct-nt. Each lane owns 8 consecutive elements
  // -> one qv2 ushort covers both chunks. Group: 4 -> 3 vmem instrs,
  // one magic-div instead of two. Skeleton unchanged from R7.
  auto STAGE = [&](int t, int bb) {
    const int tc = (t < ntiles) ? t : ntiles - 1;   // exact fit: no-op clamp
    const int cb = tc * TILE_CHUNKS + wave * 128 + 2 * lane;
    __builtin_amdgcn_global_load_lds(
        (const __attribute__((address_space(1))) void*)(const void*)(preds4 + cb),
        (__attribute__((address_space(3))) void*)(void*)&buf[bb][wave * 64],
        16, 0, 0);
    pr[bb] = __builtin_nontemporal_load(preds4 + cb + 1);
    const unsigned e = (unsigned)(cb << 2);
    const unsigned f = e / 50u;                       // magic-mul
    const unsigned q = qv2[f];
    uu[bb] = (t < ntiles) ? q : 0xFFFFu;
    jj[bb] = (int)(e - f * 50u);
  };

  auto COMPUTE = [&](int bb) {
    const vf4 pa = buf[bb][wave * 64 + lane];         // ds_read_b128
    consume8(pa, pr[bb], uu[bb], jj[bb], s_tab, num, cnt);
  };

  // wave-private pipeline, 3 tiles in flight, no barriers in the loop.
  // STEPS and all bb indices compile-time (rule #20: keep regs static).
  STAGE(blockIdx.x, 0);
  STAGE(blockIdx.x + nblocks, 1);
  STAGE(blockIdx.x + 2 * nblocks, 2);
#pragma unroll
  for (int s = 0; s < STEPS; ++s) {
    const int bb = s & 3;
    if (s + 3 < STEPS) {
      STAGE(blockIdx.x + (s + 3) * nblocks, (s + 3) & 3);
      // 3 younger groups (9 vmem ops) in flight; group s drained
      asm volatile("s_waitcnt vmcnt(9)" ::: "memory");
    } else if (s + 2 < STEPS) {
      asm volatile("s_waitcnt vmcnt(6)" ::: "memory");
    } else if (s + 1 < STEPS) {
      asm volatile("s_waitcnt vmcnt(3)" ::: "memory");
    } else {
      asm volatile("s_waitcnt vmcnt(0)" ::: "memory");
    }
    COMPUTE(bb);
  }

  // generic tails (empty at 26,214,400: exact fit, total%4==0)
  const int tid = blockIdx.x * TPB + threadIdx.x;
  const int nthreads = nblocks * TPB;
  for (int v = ntiles * TILE_CHUNKS + tid; v < nvec; v += nthreads) {
    const int e0 = v << 2;
    const unsigned f = (unsigned)e0 / 50u;
    const vf4 p = preds4[v];
    consume_chunk(p, qv2[f], e0 - (int)f * 50, s_tab, num, cnt);
  }
  for (int e = (nvec << 2) + tid; e < total; e += nthreads) {
    const unsigned f = (unsigned)e / 50u;
    const int j = e - (int)f * 50;
    const unsigned c = qv2[f] & 255u;
    if (c != 255u) {
      const unsigned qc = (c > 50u) ? 50u : c;
      int dj = j - (int)c + 3;
      dj = dj < 0 ? 0 : (dj > 7 ? 7 : dj);
      const float t = s_tab[(qc << 3) + dj];
      const float x = ((const float*)preds4)[e];
      num += softplus_stable(x) - x * t;
      cnt += 1u;
    }
  }

  // wave-64 reduction, then one atomic per block
#pragma unroll
  for (int off = 32; off > 0; off >>= 1) {
    num += __shfl_down(num, off, 64);
    cnt += __shfl_down(cnt, off, 64);
  }
  __shared__ float sn[4];
  __shared__ unsigned sc[4];
  if (lane == 0) { sn[wave] = num; sc[wave] = cnt; }
  __syncthreads();
  if (threadIdx.x == 0) {
    const float n = sn[0] + sn[1] + sn[2] + sn[3];
    const unsigned cc = sc[0] + sc[1] + sc[2] + sc[3];
    atomicAdd(&acc[0], n);
    atomicAdd((unsigned*)&acc[1], cc);
    __threadfence();
    const unsigned done = atomicAdd((unsigned*)&acc[2], 1u);
    if (done == (unsigned)nblocks - 1u) {
      const float tn = atomicAdd(&acc[0], 0.f);
      const unsigned tc = atomicAdd((unsigned*)&acc[1], 0u);
      out[0] = tn / (float)tc;
    }
  }
}

extern "C" void kernel_launch(void* const* d_in, const int* in_sizes, int n_in,
                              void* d_out, int out_size, void* d_ws, size_t ws_size,
                              hipStream_t stream) {
  const vf4* preds4 = (const vf4*)d_in[0];
  const int* gt = (const int*)d_in[1];
  float* out = (float*)d_out;
  float* acc = (float*)d_ws;                                   // 12 B
  unsigned short* qv2 = (unsigned short*)((char*)d_ws + 256);  // 1 MB
  const int total = in_sizes[0];     // 26214400
  const int nframes = in_sizes[1];   // 524288
  const int nvec = total >> 2;       // 6553600
  const int ntiles = nvec / TILE_CHUNKS;  // 12800 == GRID*STEPS

  const int pre_groups = (nframes + 3) >> 2;
  pitch_pre<<<(pre_groups + 255) / 256, 256, 0, stream>>>(
      gt, qv2, nframes, (unsigned*)acc);

  pitch_loss_main<<<GRID, TPB, 0, stream>>>(
      preds4, qv2, nvec, total, ntiles, GRID, acc, out);
}

// Round 13
// 202.441 us; speedup vs baseline: 1.3189x; 1.0037x over previous
//
#include <hip/hip_runtime.h>

#define NBINS 50
#define PAD_G 100
#define TPB 256
#define TILE_CHUNKS 512   // float4 chunks per tile per block (8 KB)
#define GRID 1280
#define STEPS 10          // GRID*STEPS*TILE_CHUNKS == nvec exactly
#define PIPE 4            // LDS buffers; 3 tiles in flight (R0/R7-proven)

typedef float vf4 __attribute__((ext_vector_type(4)));

// Gaussian kernel (5 taps, sigma=0.5), normalized
#define K0 2.6387004e-4f
#define K1 1.0645079e-1f
#define K2 7.8657085e-1f

__device__ __forceinline__ unsigned quant(int g) {
  int d = g - 50;
  d = (d < 0) ? 0 : d;
  unsigned q = __umul24((unsigned)d, 10923u) >> 16;  // exact /6 for this range
  return (q > NBINS - 1) ? (NBINS - 1) : q;
}

__device__ __forceinline__ float softplus_stable(float x) {
  return fmaxf(x, 0.f) + __logf(1.f + __expf(-fabsf(x)));
}

// qv2[f]: low byte = code(frame f), high byte = code(frame f+1); 255 = padded.
// Atomic-free (R6 lesson). Zeroes acc (replaces memset dispatch; R11-proven).
__global__ __launch_bounds__(256) void pitch_pre(
    const int* __restrict__ gt, unsigned short* __restrict__ qv2, int n,
    unsigned* __restrict__ acc)
{
  if (blockIdx.x == 0 && threadIdx.x < 3) acc[threadIdx.x] = 0u;
  const int base = (blockIdx.x * blockDim.x + threadIdx.x) << 2;
  if (base >= n) return;
  if (base + 4 <= n) {
    const int4 g = *reinterpret_cast<const int4*>(gt + base);
    const int g4 = (base + 4 < n) ? gt[base + 4] : gt[n - 1];
    const unsigned c0 = (g.x == PAD_G) ? 255u : quant(g.x);
    const unsigned c1 = (g.y == PAD_G) ? 255u : quant(g.y);
    const unsigned c2 = (g.z == PAD_G) ? 255u : quant(g.z);
    const unsigned c3 = (g.w == PAD_G) ? 255u : quant(g.w);
    const unsigned c4 = (g4  == PAD_G) ? 255u : quant(g4);
    ushort4 o;
    o.x = (unsigned short)(c0 | (c1 << 8));
    o.y = (unsigned short)(c1 | (c2 << 8));
    o.z = (unsigned short)(c2 | (c3 << 8));
    o.w = (unsigned short)(c3 | (c4 << 8));
    *reinterpret_cast<ushort4*>(qv2 + base) = o;
  } else {
    for (int f = base; f < n; ++f) {           // generic tail (empty here)
      const int ga = gt[f];
      const int gb = gt[(f + 1 < n) ? f + 1 : n - 1];
      const unsigned ba = (ga == PAD_G) ? 255u : quant(ga);
      const unsigned bb = (gb == PAD_G) ? 255u : quant(gb);
      qv2[f] = (unsigned short)(ba | (bb << 8));
    }
  }
}

// s_tab: 51 rows x 8 cols, zero-padded; row 50 all-zero absorbs pad code 255.
__device__ __forceinline__ void consume_chunk(
    vf4 p, unsigned q2, int j0, const float* s_tab,
    float& num, unsigned& cnt)
{
  const unsigned c0 = q2 & 255u;
  const unsigned c1 = (q2 >> 8) & 255u;
#pragma unroll
  for (int u = 0; u < 4; ++u) {
    int j = j0 + u;
    const bool wrap = (j >= NBINS);
    const unsigned c = wrap ? c1 : c0;
    j = wrap ? j - NBINS : j;
    const float x = p[u];
    const float sp = softplus_stable(x);
    const unsigned qc = (c > 50u) ? 50u : c;   // 255 -> zero row
    int dj = j - (int)c + 3;
    dj = dj < 0 ? 0 : (dj > 7 ? 7 : dj);
    const float t = s_tab[(qc << 3) + dj];
    const bool valid = (c != 255u);
    num += valid ? __builtin_fmaf(-x, t, sp) : 0.f;
    cnt += valid ? 1u : 0u;
  }
}

// select ushort rel (0..15) from 8 SGPR dwords: 7-cndmask tree + halfword pick
__device__ __forceinline__ unsigned sel_code(
    unsigned rel,
    unsigned k0, unsigned k1, unsigned k2, unsigned k3,
    unsigned k4, unsigned k5, unsigned k6, unsigned k7)
{
  const unsigned d = rel >> 1;
  const unsigned a0 = (d & 4u) ? k4 : k0;
  const unsigned a1 = (d & 4u) ? k5 : k1;
  const unsigned a2 = (d & 4u) ? k6 : k2;
  const unsigned a3 = (d & 4u) ? k7 : k3;
  const unsigned b0 = (d & 2u) ? a2 : a0;
  const unsigned b1 = (d & 2u) ? a3 : a1;
  const unsigned c  = (d & 1u) ? b1 : b0;
  return (rel & 1u) ? (c >> 16) : (c & 0xFFFFu);
}

__global__ __launch_bounds__(TPB) void pitch_loss_main(
    const vf4* __restrict__ preds4,
    const unsigned short* __restrict__ qv2,
    int nvec, int total, int ntiles, int nblocks,
    float* __restrict__ acc,     // [0]=num(float) [1]=cnt(uint) [2]=ctr(uint)
    float* __restrict__ out)
{
  __shared__ vf4 buf[PIPE][TILE_CHUNKS / 2];   // 4 x 4 KB (DMA half only)
  __shared__ float s_tab[51 * 8];

  for (int idx = threadIdx.x; idx < 51 * 8; idx += TPB) {
    const int q = idx >> 3;
    const int dt = (idx & 7) - 1;
    float t = 0.f;
    if (q < NBINS && 0 <= dt && dt < 5) {
      const int j = q - 2 + dt;
      if (0 <= j && j < NBINS) {
        const float kk[5] = {K0, K1, K2, K1, K0};
#pragma unroll
        for (int i = 0; i < 5; ++i) {
          int m = j - 2 + i;
          m = (m < 0) ? -m : m;
          m = (m > NBINS - 1) ? 2 * (NBINS - 1) - m : m;
          if (m == q) t += kk[i];
        }
      }
    }
    s_tab[idx] = t;
  }
  __syncthreads();

  const int wave = threadIdx.x >> 6;
  const int lane = threadIdx.x & 63;

  float num = 0.f;
  unsigned cnt = 0;
  vf4 pr[PIPE];                 // direct-nt half (VGPR path)

  // R11 post-mortem: interleaved lanes doubled cachelines/instr -> 122us.
  // Dual CONTIGUOUS paths restored (R7 = 86us). This round's single change:
  // qv2 codes move from the vector-memory stream to the SCALAR (SMEM) port.
  // A wave-group's codes span <=12 consecutive frames from a wave-uniform
  // base -> one s_load burst (8 dwords = 16 frames) per group, issued one
  // step ahead, consumed after lgkmcnt(0)+sched_barrier (rule 18). vmem
  // instrs/group: 4 -> 2 (big DMA + big direct only), coalescing unchanged.
  const unsigned nlim = (unsigned)total / 50u - 16u;   // nframes - 16

  unsigned k0, k1, k2, k3, k4, k5, k6, k7;   // SMEM slot (SGPRs)
  unsigned fb_pend = 0;

  auto STAGE_VM = [&](int t, int bb) {
    const int tc = (t < ntiles) ? t : ntiles - 1;   // exact fit: no-op clamp
    const int cb = tc * TILE_CHUNKS + wave * 128 + lane;
    __builtin_amdgcn_global_load_lds(
        (const __attribute__((address_space(1))) void*)(const void*)(preds4 + cb),
        (__attribute__((address_space(3))) void*)(void*)&buf[bb][wave * 64],
        16, 0, 0);
    pr[bb] = __builtin_nontemporal_load(preds4 + cb + 64);
  };

  auto ISSUE_SMEM = [&](int t) -> unsigned {
    const int tc = (t < ntiles) ? t : ntiles - 1;
    const unsigned ebase = (unsigned)((tc * TILE_CHUNKS + wave * 128) << 2);
    unsigned fb = ebase / 50u;                       // magic-mul (VALU)
    fb = __builtin_amdgcn_readfirstlane(fb) & ~1u;   // -> SGPR, 4B-align
    fb = (fb > nlim) ? nlim : fb;                    // SALU clamp: reads stay
    const unsigned short* sp = qv2 + fb;             //   in-bounds (rel<=15)
    asm volatile(
        "s_load_dword %0, %8, 0x0\n\t"
        "s_load_dword %1, %8, 0x4\n\t"
        "s_load_dword %2, %8, 0x8\n\t"
        "s_load_dword %3, %8, 0xc\n\t"
        "s_load_dword %4, %8, 0x10\n\t"
        "s_load_dword %5, %8, 0x14\n\t"
        "s_load_dword %6, %8, 0x18\n\t"
        "s_load_dword %7, %8, 0x1c"
        : "=s"(k0), "=s"(k1), "=s"(k2), "=s"(k3),
          "=s"(k4), "=s"(k5), "=s"(k6), "=s"(k7)
        : "s"(sp) : "memory");
    return fb;
  };

  // prologue: SMEM for group 0; vector stage for groups 0..2
  fb_pend = ISSUE_SMEM(blockIdx.x);
  STAGE_VM(blockIdx.x, 0);
  STAGE_VM(blockIdx.x + nblocks, 1);
  STAGE_VM(blockIdx.x + 2 * nblocks, 2);

#pragma unroll
  for (int s = 0; s < STEPS; ++s) {
    const int bb = s & 3;
    // group-s SMEM (issued last iter, ~20K cy ago) -> wait is free
    asm volatile("s_waitcnt lgkmcnt(0)" ::: "memory");
    __builtin_amdgcn_sched_barrier(0);     // rule 18: no hoist past the wait
    const unsigned c0 = k0, c1 = k1, c2 = k2, c3 = k3;
    const unsigned c4 = k4, c5 = k5, c6 = k6, c7 = k7;
    const unsigned fbc = fb_pend;
    if (s + 1 < STEPS) fb_pend = ISSUE_SMEM(blockIdx.x + (s + 1) * nblocks);
    if (s + 3 < STEPS) {
      STAGE_VM(blockIdx.x + (s + 3) * nblocks, (s + 3) & 3);
      // 3 younger groups (6 vmem ops) in flight; group s drained
      asm volatile("s_waitcnt vmcnt(6)" ::: "memory");
    } else if (s + 2 < STEPS) {
      asm volatile("s_waitcnt vmcnt(4)" ::: "memory");
    } else if (s + 1 < STEPS) {
      asm volatile("s_waitcnt vmcnt(2)" ::: "memory");
    } else {
      asm volatile("s_waitcnt vmcnt(0)" ::: "memory");
    }
    // compute group s
    const int t = blockIdx.x + s * nblocks;
    const int tc = (t < ntiles) ? t : ntiles - 1;
    const int cb = tc * TILE_CHUNKS + wave * 128 + lane;
    const unsigned e0 = (unsigned)(cb << 2);
    const unsigned f0 = e0 / 50u;
    const int j00 = (int)(e0 - f0 * 50u);
    unsigned w0 = sel_code(f0 - fbc, c0, c1, c2, c3, c4, c5, c6, c7);
    const unsigned e1 = e0 + 256u;
    const unsigned f1 = e1 / 50u;
    const int j01 = (int)(e1 - f1 * 50u);
    unsigned w1 = sel_code(f1 - fbc, c0, c1, c2, c3, c4, c5, c6, c7);
    if (t >= ntiles) { w0 = 0xFFFFu; w1 = 0xFFFFu; }   // vestigial (exact fit)
    const vf4 p0 = buf[bb][wave * 64 + lane];          // ds_read_b128
    consume_chunk(p0, w0, j00, s_tab, num, cnt);
    consume_chunk(pr[bb], w1, j01, s_tab, num, cnt);
  }

  // generic tails (empty at 26,214,400: exact fit, total%4==0)
  const int tid = blockIdx.x * TPB + threadIdx.x;
  const int nthreads = nblocks * TPB;
  for (int v = ntiles * TILE_CHUNKS + tid; v < nvec; v += nthreads) {
    const int e0 = v << 2;
    const unsigned f = (unsigned)e0 / 50u;
    const vf4 p = preds4[v];
    consume_chunk(p, qv2[f], e0 - (int)f * 50, s_tab, num, cnt);
  }
  for (int e = (nvec << 2) + tid; e < total; e += nthreads) {
    const unsigned f = (unsigned)e / 50u;
    const int j = e - (int)f * 50;
    const unsigned c = qv2[f] & 255u;
    if (c != 255u) {
      const unsigned qc = (c > 50u) ? 50u : c;
      int dj = j - (int)c + 3;
      dj = dj < 0 ? 0 : (dj > 7 ? 7 : dj);
      const float t = s_tab[(qc << 3) + dj];
      const float x = ((const float*)preds4)[e];
      num += softplus_stable(x) - x * t;
      cnt += 1u;
    }
  }

  // wave-64 reduction, then one atomic per block
#pragma unroll
  for (int off = 32; off > 0; off >>= 1) {
    num += __shfl_down(num, off, 64);
    cnt += __shfl_down(cnt, off, 64);
  }
  __shared__ float sn[4];
  __shared__ unsigned sc[4];
  if (lane == 0) { sn[wave] = num; sc[wave] = cnt; }
  __syncthreads();
  if (threadIdx.x == 0) {
    const float n = sn[0] + sn[1] + sn[2] + sn[3];
    const unsigned cc = sc[0] + sc[1] + sc[2] + sc[3];
    atomicAdd(&acc[0], n);
    atomicAdd((unsigned*)&acc[1], cc);
    __threadfence();
    const unsigned done = atomicAdd((unsigned*)&acc[2], 1u);
    if (done == (unsigned)nblocks - 1u) {
      const float tn = atomicAdd(&acc[0], 0.f);
      const unsigned tc2 = atomicAdd((unsigned*)&acc[1], 0u);
      out[0] = tn / (float)tc2;
    }
  }
}

extern "C" void kernel_launch(void* const* d_in, const int* in_sizes, int n_in,
                              void* d_out, int out_size, void* d_ws, size_t ws_size,
                              hipStream_t stream) {
  const vf4* preds4 = (const vf4*)d_in[0];
  const int* gt = (const int*)d_in[1];
  float* out = (float*)d_out;
  float* acc = (float*)d_ws;                                   // 12 B
  unsigned short* qv2 = (unsigned short*)((char*)d_ws + 256);  // 1 MB
  const int total = in_sizes[0];     // 26214400
  const int nframes = in_sizes[1];   // 524288
  const int nvec = total >> 2;       // 6553600
  const int ntiles = nvec / TILE_CHUNKS;  // 12800 == GRID*STEPS

  const int pre_groups = (nframes + 3) >> 2;
  pitch_pre<<<(pre_groups + 255) / 256, 256, 0, stream>>>(
      gt, qv2, nframes, (unsigned*)acc);

  pitch_loss_main<<<GRID, TPB, 0, stream>>>(
      preds4, qv2, nvec, total, ntiles, GRID, acc, out);
}